// Round 2
// 235.695 us; speedup vs baseline: 1.0168x; 1.0168x over previous
//
#include <hip/hip_runtime.h>

#define L_SEQ 1024
#define EMB 1024
#define NH 16
#define HD 64

typedef _Float16 half8 __attribute__((ext_vector_type(8)));
typedef _Float16 half4v __attribute__((ext_vector_type(4)));
typedef __fp16 h2 __attribute__((ext_vector_type(2)));
typedef float f32x4 __attribute__((ext_vector_type(4)));
typedef float fvec4 __attribute__((ext_vector_type(4)));
typedef unsigned int u32;
typedef unsigned long long u64;

constexpr float C2 = 0.045084220027780106f;   // SCALE * log2(e) -- folded into K16 prepass

constexpr int FP = 40;   // fc LDS pitch
constexpr int PP = 72;   // P_lds pitch

__device__ __forceinline__ void async16(const void* g, void* l) {
    __builtin_amdgcn_global_load_lds((const __attribute__((address_space(1))) u32*)g,
                                     (__attribute__((address_space(3))) u32*)l, 16, 0, 0);
}

// ---------------------------------------------------------------------------
// Prepass: pack attn_mask into bitmask; blocks 0..31 also pack pad mask
// ---------------------------------------------------------------------------
__global__ void pack_mask_kernel(const int* __restrict__ am, u32* __restrict__ bits,
                                 const int* __restrict__ pad, u32* __restrict__ pbits) {
    const int i = blockIdx.x * 256 + threadIdx.x;
    const int lane = threadIdx.x & 63;
    u64 b = __ballot(am[i] != 0);
    if (lane == 0)       bits[i >> 5] = (u32)b;
    else if (lane == 32) bits[i >> 5] = (u32)(b >> 32);
    if (blockIdx.x < 32) {   // 8*1024 pad ints
        const int j = blockIdx.x * 256 + threadIdx.x;
        u64 pb = __ballot(pad[j] != 0);
        if (lane == 0)       pbits[j >> 5] = (u32)pb;
        else if (lane == 32) pbits[j >> 5] = (u32)(pb >> 32);
    }
}

// ---------------------------------------------------------------------------
// Prepass: fc_w fp32 -> f16
// ---------------------------------------------------------------------------
__global__ void convert_w_kernel(const float* __restrict__ w, _Float16* __restrict__ o) {
    size_t i = ((size_t)blockIdx.x * blockDim.x + threadIdx.x) * 4;
    fvec4 v = *(const fvec4*)(w + i);
    half4v h;
#pragma unroll
    for (int j = 0; j < 4; ++j) h[j] = (_Float16)v[j];
    *(half4v*)(o + i) = h;
}

// ---------------------------------------------------------------------------
// Prepass: K -> f16 head-blocked (nh, k, d) scaled by C2; V -> f16 transposed
// ---------------------------------------------------------------------------
__global__ __launch_bounds__(256) void cvt_kv_kernel(
    const float* __restrict__ keys, const float* __restrict__ values,
    _Float16* __restrict__ K16, _Float16* __restrict__ Vt16)
{
    __shared__ __align__(16) _Float16 Vt[64 * PP];
    const int tid = threadIdx.x;
    const int kt = blockIdx.x, h = blockIdx.y, n = blockIdx.z;
    const int kbase = kt * 64;
    const int r = tid >> 2, c0 = (tid & 3) * 16;
    const int nh = n * NH + h;

    {   // K: reorder rows into head-blocked, convert, fold C2
        const float* src = keys + ((size_t)(n * L_SEQ + kbase + r)) * EMB + h * HD + c0;
        fvec4 a0 = *(const fvec4*)(src),     a1 = *(const fvec4*)(src + 4);
        fvec4 a2 = *(const fvec4*)(src + 8), a3 = *(const fvec4*)(src + 12);
        half8 o0, o1;
#pragma unroll
        for (int j = 0; j < 4; ++j) {
            o0[j] = (_Float16)(a0[j] * C2); o0[j + 4] = (_Float16)(a1[j] * C2);
            o1[j] = (_Float16)(a2[j] * C2); o1[j + 4] = (_Float16)(a3[j] * C2);
        }
        _Float16* dst = K16 + ((size_t)nh * L_SEQ + kbase + r) * HD + c0;
        *(half8*)dst = o0; *(half8*)(dst + 8) = o1;
    }
    {   // V: stage transposed tile in LDS
        const float* src = values + ((size_t)(n * L_SEQ + kbase + r)) * EMB + h * HD + c0;
        fvec4 vv[4];
        vv[0] = *(const fvec4*)(src);     vv[1] = *(const fvec4*)(src + 4);
        vv[2] = *(const fvec4*)(src + 8); vv[3] = *(const fvec4*)(src + 12);
#pragma unroll
        for (int i = 0; i < 16; ++i)
            Vt[(c0 + i) * PP + r] = (_Float16)vv[i >> 2][i & 3];
    }
    __syncthreads();
    {   // write Vt16 rows (d-major)
        const int d = tid >> 2, k0 = (tid & 3) * 16;
        half8 v0 = *(const half8*)(&Vt[d * PP + k0]);
        half8 v1 = *(const half8*)(&Vt[d * PP + k0 + 8]);
        _Float16* dst = Vt16 + ((size_t)nh * HD + d) * L_SEQ + kbase + k0;
        *(half8*)dst = v0; *(half8*)(dst + 8) = v1;
    }
}

// ---------------------------------------------------------------------------
// Fused masked attention, S^T formulation.
// Double-buffered K/V staging (DMA for kt+1 overlaps compute of kt, ONE
// barrier per tile), mask applied as packed-f16 {0,1} multiply via
// conflict-free 16-entry LDS table, cvt_pkrtz pack, v_dot2 row sums.
// ---------------------------------------------------------------------------
__global__ __launch_bounds__(256, 3) void attn_kernel(
    const _Float16* __restrict__ K16, const _Float16* __restrict__ Vt16,
    const float* __restrict__ queries, const u32* __restrict__ mbits,
    const u32* __restrict__ pbits, _Float16* __restrict__ out_f16)
{
    __shared__ __align__(16) _Float16 K_lds[2][64 * 64];   // XOR-swizzled, double-buffered
    __shared__ __align__(16) _Float16 V_lds[2][64 * 64];   // V^T tile, XOR-swizzled, dbuf
    __shared__ __align__(16) _Float16 P_lds[128 * PP];
    __shared__ __align__(8)  u32 mtab[32];                 // 4 mask bits -> packed f16 {0,1}x4

    const int tid  = threadIdx.x;
    const int lane = tid & 63;
    const int wave = tid >> 6;
    const int l16  = lane & 15;
    const int quad = lane >> 4;
    const int bid  = blockIdx.x;
    const int nh = bid & 127, qt = bid >> 7;
    const int n = nh >> 4, h = nh & 15;
    const int qbase = qt * 128;
    const int xr = l16 & 7;
    const int quad4 = quad * 4;

    const _Float16* Kt_base = K16 + (size_t)nh * L_SEQ * HD;
    const _Float16* Vt_base = Vt16 + (size_t)nh * HD * L_SEQ;
    const int gch = (lane & 7) ^ ((lane >> 3) & 7);      // XOR-swizzled source chunk

    auto stage = [&](int buf, int kt) {
        const int kbase = kt * 64;
#pragma unroll
        for (int s2 = 0; s2 < 2; ++s2) {
            const int row = wave * 16 + s2 * 8 + (lane >> 3);
            async16(Kt_base + (size_t)(kbase + row) * HD + gch * 8,
                    &K_lds[buf][(wave * 16 + s2 * 8) * 64]);
            async16(Vt_base + (size_t)row * L_SEQ + kbase + gch * 8,
                    &V_lds[buf][(wave * 16 + s2 * 8) * 64]);
        }
    };

    stage(0, 0);   // prefetch tile 0 under Q setup

    if (tid < 16) {
        mtab[tid * 2]     = ((tid & 1) ? 0x3C00u : 0u) | ((tid & 2) ? 0x3C000000u : 0u);
        mtab[tid * 2 + 1] = ((tid & 4) ? 0x3C00u : 0u) | ((tid & 8) ? 0x3C000000u : 0u);
    }

    // --- Q fragments (B operand for S^T)
    half8 qf[2][2];
#pragma unroll
    for (int s = 0; s < 2; ++s) {
        const int qrow = qbase + wave * 32 + s * 16 + l16;
        const float* qp = queries + ((size_t)(n * L_SEQ + qrow)) * EMB + h * HD;
#pragma unroll
        for (int t = 0; t < 2; ++t) {
            fvec4 a = *(const fvec4*)(qp + t * 32 + quad * 8);
            fvec4 b = *(const fvec4*)(qp + t * 32 + quad * 8 + 4);
#pragma unroll
            for (int j = 0; j < 4; ++j) { qf[s][t][j] = (_Float16)a[j]; qf[s][t][j + 4] = (_Float16)b[j]; }
        }
    }

    f32x4 Ov[2][4];
#pragma unroll
    for (int s = 0; s < 2; ++s)
#pragma unroll
        for (int dt = 0; dt < 4; ++dt) Ov[s][dt] = (f32x4){0.f, 0.f, 0.f, 0.f};
    float lsum[2] = {0.f, 0.f};
    const h2 one2 = {(__fp16)1.f, (__fp16)1.f};

    int cur = 0;
#pragma unroll 2
    for (int kt = 0; kt < L_SEQ / 64; ++kt) {
        __syncthreads();                                  // tile kt landed; prior reads done
        if (kt + 1 < L_SEQ / 64) stage(cur ^ 1, kt + 1);  // DMA kt+1 overlaps compute kt

        uint2 wm[2];
#pragma unroll
        for (int s = 0; s < 2; ++s) {
            const int qrow = qbase + wave * 32 + s * 16 + l16;
            wm[s] = *(const uint2*)(&mbits[qrow * 32 + kt * 2]);
        }
        const u32 plo = pbits[(n << 5) + (kt << 1)];
        const u32 phi = pbits[(n << 5) + (kt << 1) + 1];

        // --- S^T = K * Q^T  (C2 pre-folded into K16)
        f32x4 S[2][4];
#pragma unroll
        for (int s = 0; s < 2; ++s)
#pragma unroll
            for (int tj = 0; tj < 4; ++tj) S[s][tj] = (f32x4){0.f, 0.f, 0.f, 0.f};

        const _Float16* kb = &K_lds[cur][0];
#pragma unroll
        for (int tj = 0; tj < 4; ++tj) {
            const _Float16* kr = kb + (tj * 16 + l16) * 64;
            const int c0 = (quad ^ xr) * 8;
            half8 k0 = *(const half8*)(kr + c0);
            half8 k1 = *(const half8*)(kr + (c0 ^ 32));
            S[0][tj] = __builtin_amdgcn_mfma_f32_16x16x32_f16(k0, qf[0][0], S[0][tj], 0, 0, 0);
            S[0][tj] = __builtin_amdgcn_mfma_f32_16x16x32_f16(k1, qf[0][1], S[0][tj], 0, 0, 0);
            S[1][tj] = __builtin_amdgcn_mfma_f32_16x16x32_f16(k0, qf[1][0], S[1][tj], 0, 0, 0);
            S[1][tj] = __builtin_amdgcn_mfma_f32_16x16x32_f16(k1, qf[1][1], S[1][tj], 0, 0, 0);
        }

        // --- p = exp2(S) * m, m in {0,1} from LDS table (broadcast, conflict-free);
        //     masked p == 0 exactly (ref masked term ~3e-14, negligible)
#pragma unroll
        for (int s = 0; s < 2; ++s) {
            const u32 pw0 = wm[s].x & plo, pw1 = wm[s].y & phi;
#pragma unroll
            for (int tj = 0; tj < 4; ++tj) {
                const u32 m4 = (((tj & 2) ? pw1 : pw0) >> ((tj & 1) * 16 + quad4)) & 15u;
                const uint2 mm = *(const uint2*)(&mtab[m4 * 2]);
                const float p0 = __builtin_amdgcn_exp2f(S[s][tj][0]);
                const float p1 = __builtin_amdgcn_exp2f(S[s][tj][1]);
                const float p2 = __builtin_amdgcn_exp2f(S[s][tj][2]);
                const float p3 = __builtin_amdgcn_exp2f(S[s][tj][3]);
                const h2 q01 = __builtin_amdgcn_cvt_pkrtz(p0, p1) * __builtin_bit_cast(h2, mm.x);
                const h2 q23 = __builtin_amdgcn_cvt_pkrtz(p2, p3) * __builtin_bit_cast(h2, mm.y);
                lsum[s] = __builtin_amdgcn_fdot2(q01, one2, lsum[s], false);
                lsum[s] = __builtin_amdgcn_fdot2(q23, one2, lsum[s], false);
                uint2 st;
                st.x = __builtin_bit_cast(u32, q01);
                st.y = __builtin_bit_cast(u32, q23);
                *(uint2*)(&P_lds[(wave * 32 + s * 16 + l16) * PP + tj * 16 + quad4]) = st;
            }
        }

        // --- O += P * V  (P region wave-private: no barrier needed)
        const _Float16* vb = &V_lds[cur][0];
        half8 pf0[2], pf1[2];
#pragma unroll
        for (int t = 0; t < 2; ++t) {
            pf0[t] = *(const half8*)(&P_lds[(wave * 32 + l16) * PP + t * 32 + quad * 8]);
            pf1[t] = *(const half8*)(&P_lds[(wave * 32 + 16 + l16) * PP + t * 32 + quad * 8]);
        }
#pragma unroll
        for (int t = 0; t < 2; ++t) {
            const int c0 = ((t * 4 + quad) ^ xr) * 8;
#pragma unroll
            for (int dt = 0; dt < 4; ++dt) {
                half8 vf = *(const half8*)(&vb[(dt * 16 + l16) * 64 + c0]);
                Ov[0][dt] = __builtin_amdgcn_mfma_f32_16x16x32_f16(pf0[t], vf, Ov[0][dt], 0, 0, 0);
                Ov[1][dt] = __builtin_amdgcn_mfma_f32_16x16x32_f16(pf1[t], vf, Ov[1][dt], 0, 0, 0);
            }
        }
        cur ^= 1;
    }

    // --- epilogue: reduce row-sums across quads, normalize, store
#pragma unroll
    for (int s = 0; s < 2; ++s) {
        lsum[s] += __shfl_xor(lsum[s], 16);
        lsum[s] += __shfl_xor(lsum[s], 32);
    }
#pragma unroll
    for (int s = 0; s < 2; ++s)
#pragma unroll
        for (int reg = 0; reg < 4; ++reg) {
            const float linv = 1.0f / fmaxf(__shfl(lsum[s], quad4 + reg), 1e-25f);
            const int qrow = qbase + wave * 32 + s * 16 + quad4 + reg;
            _Float16* op = out_f16 + ((size_t)(n * L_SEQ + qrow)) * EMB + h * HD;
#pragma unroll
            for (int dt = 0; dt < 4; ++dt)
                op[dt * 16 + l16] = (_Float16)(Ov[s][dt][reg] * linv);
        }
}

// ---------------------------------------------------------------------------
// FC: C[8192][1024] = A(f16) * W^T(f16) + bias, 128x128 tile, BK=32
// ---------------------------------------------------------------------------
__global__ __launch_bounds__(256) void fc_kernel(
    const _Float16* __restrict__ A, const _Float16* __restrict__ W,
    const float* __restrict__ bias, float* __restrict__ C)
{
    __shared__ __align__(16) _Float16 As[128 * FP];
    __shared__ __align__(16) _Float16 Ws[128 * FP];

    const int tid = threadIdx.x;
    const int lane = tid & 63;
    const int wv = tid >> 6;
    const int l16 = lane & 15;
    const int quad = lane >> 4;
    const int wm = (wv >> 1) * 64, wn = (wv & 1) * 64;
    const int Mb = blockIdx.x * 128, Nb = blockIdx.y * 128;

    f32x4 acc[4][4];
#pragma unroll
    for (int i = 0; i < 4; ++i)
#pragma unroll
        for (int j = 0; j < 4; ++j) acc[i][j] = (f32x4){0.f, 0.f, 0.f, 0.f};

    for (int k0 = 0; k0 < EMB; k0 += 32) {
        __syncthreads();
#pragma unroll
        for (int s = 0; s < 2; ++s) {
            const int id = tid + s * 256;
            const int row = id >> 2, ch = (id & 3) * 8;
            *(half8*)(&As[row * FP + ch]) = *(const half8*)(A + (size_t)(Mb + row) * EMB + k0 + ch);
            *(half8*)(&Ws[row * FP + ch]) = *(const half8*)(W + (size_t)(Nb + row) * EMB + k0 + ch);
        }
        __syncthreads();

        half8 af[4], bf[4];
#pragma unroll
        for (int i = 0; i < 4; ++i) {
            af[i] = *(const half8*)(&As[(wm + i * 16 + l16) * FP + quad * 8]);
            bf[i] = *(const half8*)(&Ws[(wn + i * 16 + l16) * FP + quad * 8]);
        }
#pragma unroll
        for (int i = 0; i < 4; ++i)
#pragma unroll
            for (int j = 0; j < 4; ++j)
                acc[i][j] = __builtin_amdgcn_mfma_f32_16x16x32_f16(af[i], bf[j], acc[i][j], 0, 0, 0);
    }

#pragma unroll
    for (int i = 0; i < 4; ++i) {
        const int m = Mb + wm + i * 16 + quad * 4;
#pragma unroll
        for (int j = 0; j < 4; ++j) {
            const int jc = Nb + wn + j * 16 + l16;
            const float b = bias[jc];
#pragma unroll
            for (int reg = 0; reg < 4; ++reg)
                C[(size_t)(m + reg) * EMB + jc] = acc[i][j][reg] + b;
        }
    }
}

// ---------------------------------------------------------------------------
extern "C" void kernel_launch(void* const* d_in, const int* in_sizes, int n_in,
                              void* d_out, int out_size, void* d_ws, size_t ws_size,
                              hipStream_t stream) {
    const float* values  = (const float*)d_in[0];
    const float* keys    = (const float*)d_in[1];
    const float* queries = (const float*)d_in[2];
    const float* fc_w    = (const float*)d_in[3];
    const float* fc_b    = (const float*)d_in[4];
    const int*   amask   = (const int*)d_in[5];
    const int*   pmask   = (const int*)d_in[6];
    float* out = (float*)d_out;

    // ws: [0,16M) attn_out f16 | [16M,18M) W f16 | [18M,+128K) mbits |
    //     [18M+128K,+1K) pbits | [19M,35M) K16 | [35M,51M) Vt16
    char* w = (char*)d_ws;
    _Float16* attn_out = (_Float16*)w;
    _Float16* w_f16    = (_Float16*)(w + (size_t)16 * 1024 * 1024);
    u32*      mbits    = (u32*)(w + (size_t)18 * 1024 * 1024);
    u32*      pbits    = (u32*)(w + (size_t)18 * 1024 * 1024 + 128 * 1024);
    _Float16* K16      = (_Float16*)(w + (size_t)19 * 1024 * 1024);
    _Float16* Vt16     = (_Float16*)(w + (size_t)35 * 1024 * 1024);

    pack_mask_kernel<<<4096, 256, 0, stream>>>(amask, mbits, pmask, pbits);
    convert_w_kernel<<<1024, 256, 0, stream>>>(fc_w, w_f16);
    cvt_kv_kernel<<<dim3(16, 16, 8), 256, 0, stream>>>(keys, values, K16, Vt16);
    attn_kernel<<<1024, 256, 0, stream>>>(K16, Vt16, queries, mbits, pbits, attn_out);
    fc_kernel<<<dim3(64, 8), 256, 0, stream>>>(attn_out, w_f16, fc_b, out);
}